// Round 9
// baseline (139.608 us; speedup 1.0000x reference)
//
#include <hip/hip_runtime.h>
#include <stdint.h>

#define NAC 147456   // 128*128*9
#define NGT 64
#define NB  8
#define APT 6        // anchors per thread in k1
#define BLK 256
#define GX  (NAC / (BLK * APT))   // 96 -> grid 96x8 = 768 blocks = 3/CU exact

// ---------------- Threefry-2x32 (JAX-compatible, 20 rounds) ----------------
__host__ __device__ static inline uint32_t tf_rotl(uint32_t x, uint32_t d) {
  return (x << d) | (x >> (32u - d));
}

__host__ __device__ static inline void threefry2x32(
    uint32_t k0, uint32_t k1, uint32_t x0, uint32_t x1,
    uint32_t* o0, uint32_t* o1)
{
  const uint32_t ks2 = k0 ^ k1 ^ 0x1BD11BDAu;
  x0 += k0; x1 += k1;
#define TFR(r) { x0 += x1; x1 = tf_rotl(x1, (r)); x1 ^= x0; }
  TFR(13u) TFR(15u) TFR(26u) TFR(6u)   x0 += k1;  x1 += ks2 + 1u;
  TFR(17u) TFR(29u) TFR(16u) TFR(24u)  x0 += ks2; x1 += k0 + 2u;
  TFR(13u) TFR(15u) TFR(26u) TFR(6u)   x0 += k0;  x1 += k1 + 3u;
  TFR(17u) TFR(29u) TFR(16u) TFR(24u)  x0 += k1;  x1 += ks2 + 4u;
  TFR(13u) TFR(15u) TFR(26u) TFR(6u)   x0 += ks2; x1 += k0 + 5u;
#undef TFR
  *o0 = x0; *o1 = x1;
}

__device__ static inline void bbox2delta_store(
    const float4& a, const float4& g, float* dst)
{
  const float wr  = a.w - a.y,          hr  = a.z - a.x;
  const float xcr = a.y + 0.5f * wr,    ycr = a.x + 0.5f * hr;
  const float wrc = fmaxf(wr, 1e-5f),   hrc = fmaxf(hr, 1e-5f);
  const float wl  = g.w - g.y,          hl  = g.z - g.x;
  const float xcl = g.y + 0.5f * wl,    ycl = g.x + 0.5f * hl;
  float4 r;
  r.x = fminf(fmaxf((xcl - xcr) / wrc, -10.0f), 10.0f);
  r.y = fminf(fmaxf((ycl - ycr) / hrc, -10.0f), 10.0f);
  r.z = fminf(fmaxf(__logf(wl / wrc),  -10.0f), 10.0f);
  r.w = fminf(fmaxf(__logf(hl / hrc),  -10.0f), 10.0f);
  *reinterpret_cast<float4*>(dst) = r;
}

// ---------------- Kernel 1: IoU argmax + proposals + flags + block count -----
// APT=6: 768 blocks = exactly 3/CU, 24 independent div chains per thread —
// saturates the VALU pipe at low occupancy and amortizes per-j overhead.
// NO min-waves launch bound (round 7: a register cap spills state, +30 MB).
// best init = 0/bidx = 0 is exact (iou >= 0; strict > keeps first-max);
// IoU expression is FMA-contraction-free with IEEE div => decisions
// bit-identical to the fp32 numpy reference.
template <bool USE_FLAGS>
__global__ __launch_bounds__(BLK) void k1_classify(
    const float* __restrict__ anchors,
    const float* __restrict__ gt,
    const float* __restrict__ deltas,
    float* __restrict__ out,
    int* __restrict__ cnt_blk,          // USE_FLAGS: [NB*GX]; else counts[NB]
    unsigned char* __restrict__ flags)
{
  __shared__ float4 gbox[NGT];
  __shared__ float  garea[NGT];
  __shared__ int    s_cnt;
  const int b   = blockIdx.y;
  const int tid = threadIdx.x;

  if (tid == 0) s_cnt = 0;
  if (tid < NGT) {
    float4 g = reinterpret_cast<const float4*>(gt)[b * NGT + tid];
    gbox[tid]  = g;
    garea[tid] = fmaxf(g.z - g.x, 0.0f) * fmaxf(g.w - g.y, 0.0f);
  }
  __syncthreads();

  const int base = blockIdx.x * (BLK * APT) + tid;

  float4 a[APT];
  float  areaA[APT], best[APT];
  int    bidx[APT];
#pragma unroll
  for (int t = 0; t < APT; ++t) {
    a[t] = reinterpret_cast<const float4*>(anchors)[base + t * BLK];
    areaA[t] = fmaxf(a[t].z - a[t].x, 0.0f) * fmaxf(a[t].w - a[t].y, 0.0f);
    best[t] = 0.0f;
    bidx[t] = 0;
  }

#pragma unroll 4
  for (int j = 0; j < NGT; ++j) {
    const float4 g  = gbox[j];
    const float  ga = garea[j];
#pragma unroll
    for (int t = 0; t < APT; ++t) {
      float yi = fmaxf(a[t].x, g.x);
      float xi = fmaxf(a[t].y, g.y);
      float ya = fminf(a[t].z, g.z);
      float xa = fminf(a[t].w, g.w);
      float inter = fmaxf(ya - yi, 0.0f) * fmaxf(xa - xi, 0.0f);
      float den   = ((areaA[t] + ga) - inter) + 1e-5f;   // union + EPS, exact order
      float iou   = (10000.0f * inter) / den;            // IEEE div
      bool upd = iou > best[t];                          // first-max == jnp.argmax
      best[t] = upd ? iou : best[t];
      bidx[t] = upd ? j   : bidx[t];
    }
  }

  int npos = 0;
#pragma unroll
  for (int t = 0; t < APT; ++t) {
    const int i = base + t * BLK;
    const bool pos = best[t] > 5000.0f;

    const float4 d = reinterpret_cast<const float4*>(deltas)[b * NAC + i];
    const float wb = a[t].w - a[t].y, hb = a[t].z - a[t].x;
    const float xc = a[t].y + 0.5f * wb + wb * d.x;
    const float yc = a[t].x + 0.5f * hb + hb * d.y;
    const float w_ = wb * __expf(d.z);
    const float h_ = hb * __expf(d.w);

    float* rowp = out + ((size_t)b * NAC + i) * 8;
    reinterpret_cast<float4*>(rowp)[0] =
        make_float4(yc - 0.5f * h_, xc - 0.5f * w_, yc + 0.5f * h_, xc + 0.5f * w_);
    if (USE_FLAGS) {
      reinterpret_cast<float4*>(rowp)[1] = make_float4(0.f, 0.f, 0.f, 0.f);
      flags[(size_t)b * NAC + i] = pos ? (unsigned char)(bidx[t] + 1) : 0u;
    } else {
      reinterpret_cast<float4*>(rowp)[1] =
          make_float4(pos ? (float)(bidx[t] + 1) : 0.0f, 0.f, 0.f, 0.f);
    }

    unsigned long long m = __ballot(pos);
    if ((tid & 63) == 0) npos += (int)__popcll(m);
  }
  if ((tid & 63) == 0 && npos)
    atomicAdd(&s_cnt, npos);
  __syncthreads();

  if (tid == 0) {
    if (USE_FLAGS) cnt_blk[b * GX + blockIdx.x] = s_cnt;  // written once, no memset
    else if (s_cnt) atomicAdd(&cnt_blk[b], s_cnt);
  }
}

// ---------------- Kernel 2a (flags): sum block counts, sparse sampling -------
__global__ __launch_bounds__(256) void k2_flags(
    const float* __restrict__ anchors,
    const float* __restrict__ gt,
    float* __restrict__ out,
    const int* __restrict__ cnt_blk,
    const unsigned char* __restrict__ flags,
    uint32_t kp0, uint32_t kp1)
{
  __shared__ int s_tot;
  const int b   = blockIdx.y;
  const int tid = threadIdx.x;

  if (tid == 0) s_tot = 0;
  __syncthreads();
  if (tid < GX) atomicAdd(&s_tot, cnt_blk[b * GX + tid]);
  __syncthreads();
  const float th = 128.0f / ((float)s_tot + 1e-6f);

  const int chunk = blockIdx.x * 256 + tid;   // 16 rows per thread
  uint4 fv = reinterpret_cast<const uint4*>(flags + (size_t)b * NAC)[chunk];
  if ((fv.x | fv.y | fv.z | fv.w) == 0u) return;

  const uint32_t words[4] = { fv.x, fv.y, fv.z, fv.w };
  const int base_i = chunk * 16;

#pragma unroll
  for (int w = 0; w < 4; ++w) {
    uint32_t wd = words[w];
    while (wd) {
      const int byte = __ffs(wd) / 8;        // flag <= 64 keeps byte MSB clear
      const int fl   = (wd >> (byte * 8)) & 0xFF;
      wd &= ~(0xFFu << (byte * 8));
      const int i = base_i + w * 4 + byte;
      const int f = b * NAC + i;

      uint32_t o0, o1;
      threefry2x32(kp0, kp1, 0u, (uint32_t)f, &o0, &o1);
      const uint32_t bits = o0 ^ o1;
      union { uint32_t u; float flt; } cv;
      cv.u = (bits >> 9) | 0x3F800000u;
      if (cv.flt - 1.0f < th) {
        const float4 a = reinterpret_cast<const float4*>(anchors)[i];
        const float4 g = reinterpret_cast<const float4*>(gt)[b * NGT + (fl - 1)];
        bbox2delta_store(a, g, out + (size_t)f * 8 + 4);
      }
    }
  }
}

// ---------------- Kernel 2b (fallback, proven): flag in out[4] ---------------
__global__ __launch_bounds__(256) void k2_fallback(
    const float* __restrict__ anchors,
    const float* __restrict__ gt,
    float* __restrict__ out,
    const int* __restrict__ counts,
    uint32_t kp0, uint32_t kp1)
{
  const int b = blockIdx.y;
  const int i = blockIdx.x * 256 + threadIdx.x;
  const int f = b * NAC + i;
  float* rowp = out + (size_t)f * 8;

  const float flag = rowp[4];
  if (flag == 0.0f) return;

  const float th = 128.0f / ((float)counts[b] + 1e-6f);

  uint32_t o0, o1;
  threefry2x32(kp0, kp1, 0u, (uint32_t)f, &o0, &o1);
  const uint32_t bits = o0 ^ o1;
  union { uint32_t u; float flt; } cv;
  cv.u = (bits >> 9) | 0x3F800000u;

  if (cv.flt - 1.0f < th) {
    const float4 a = reinterpret_cast<const float4*>(anchors)[i];
    const float4 g = reinterpret_cast<const float4*>(gt)[b * NGT + ((int)flag - 1)];
    bbox2delta_store(a, g, rowp + 4);
  } else {
    reinterpret_cast<float4*>(rowp)[1] = make_float4(0.f, 0.f, 0.f, 0.f);
  }
}

extern "C" void kernel_launch(void* const* d_in, const int* in_sizes, int n_in,
                              void* d_out, int out_size, void* d_ws, size_t ws_size,
                              hipStream_t stream)
{
  const float* anchors = (const float*)d_in[0];
  const float* gt      = (const float*)d_in[1];
  const float* deltas  = (const float*)d_in[2];
  float* out  = (float*)d_out;
  int* cnt_blk = (int*)d_ws;                                // [NB*GX] ints
  unsigned char* flags = (unsigned char*)d_ws + 8192;       // [NB*NAC] bytes

  const bool use_flags = ws_size >= (size_t)(8192 + NB * NAC);

  // kp = jax.random.split(jax.random.key(42))[0], threefry_partitionable:
  // kp = threefry2x32((0,42), 0, 0), full pair. (Verified rounds 2/3/5/6/7/8.)
  uint32_t kp0, kp1;
  threefry2x32(0u, 42u, 0u, 0u, &kp0, &kp1);

  dim3 g1(GX, NB);   // (96, 8) = 768 blocks, 3/CU exact
  if (use_flags) {
    k1_classify<true><<<g1, dim3(BLK), 0, stream>>>(anchors, gt, deltas, out,
                                                    cnt_blk, flags);
    dim3 g2(NAC / 16 / 256, NB);   // (36, 8)
    k2_flags<<<g2, dim3(256), 0, stream>>>(anchors, gt, out, cnt_blk, flags,
                                           kp0, kp1);
  } else {
    hipMemsetAsync(cnt_blk, 0, NB * sizeof(int), stream);
    k1_classify<false><<<g1, dim3(BLK), 0, stream>>>(anchors, gt, deltas, out,
                                                     cnt_blk, nullptr);
    dim3 g2(NAC / 256, NB);        // (576, 8)
    k2_fallback<<<g2, dim3(256), 0, stream>>>(anchors, gt, out, cnt_blk,
                                              kp0, kp1);
  }
}

// Round 10
// 137.580 us; speedup vs baseline: 1.0147x; 1.0147x over previous
//
#include <hip/hip_runtime.h>
#include <stdint.h>

#define NAC 147456   // 128*128*9
#define NGT 64
#define NB  8
#define APT 3        // anchors per thread in k1 — measured optimum (round 8)
#define BLK 256
#define GX  (NAC / (BLK * APT))   // 192 -> grid 192x8 = 1536 blocks = 6/CU exact

// ---------------- Threefry-2x32 (JAX-compatible, 20 rounds) ----------------
__host__ __device__ static inline uint32_t tf_rotl(uint32_t x, uint32_t d) {
  return (x << d) | (x >> (32u - d));
}

__host__ __device__ static inline void threefry2x32(
    uint32_t k0, uint32_t k1, uint32_t x0, uint32_t x1,
    uint32_t* o0, uint32_t* o1)
{
  const uint32_t ks2 = k0 ^ k1 ^ 0x1BD11BDAu;
  x0 += k0; x1 += k1;
#define TFR(r) { x0 += x1; x1 = tf_rotl(x1, (r)); x1 ^= x0; }
  TFR(13u) TFR(15u) TFR(26u) TFR(6u)   x0 += k1;  x1 += ks2 + 1u;
  TFR(17u) TFR(29u) TFR(16u) TFR(24u)  x0 += ks2; x1 += k0 + 2u;
  TFR(13u) TFR(15u) TFR(26u) TFR(6u)   x0 += k0;  x1 += k1 + 3u;
  TFR(17u) TFR(29u) TFR(16u) TFR(24u)  x0 += k1;  x1 += ks2 + 4u;
  TFR(13u) TFR(15u) TFR(26u) TFR(6u)   x0 += ks2; x1 += k0 + 5u;
#undef TFR
  *o0 = x0; *o1 = x1;
}

__device__ static inline void bbox2delta_store(
    const float4& a, const float4& g, float* dst)
{
  const float wr  = a.w - a.y,          hr  = a.z - a.x;
  const float xcr = a.y + 0.5f * wr,    ycr = a.x + 0.5f * hr;
  const float wrc = fmaxf(wr, 1e-5f),   hrc = fmaxf(hr, 1e-5f);
  const float wl  = g.w - g.y,          hl  = g.z - g.x;
  const float xcl = g.y + 0.5f * wl,    ycl = g.x + 0.5f * hl;
  float4 r;
  r.x = fminf(fmaxf((xcl - xcr) / wrc, -10.0f), 10.0f);
  r.y = fminf(fmaxf((ycl - ycr) / hrc, -10.0f), 10.0f);
  r.z = fminf(fmaxf(__logf(wl / wrc),  -10.0f), 10.0f);
  r.w = fminf(fmaxf(__logf(hl / hrc),  -10.0f), 10.0f);
  *reinterpret_cast<float4*>(dst) = r;
}

// ---------------- Kernel 1: IoU argmax + proposals + flags + block count -----
// Round-8 measured optimum: APT=3 => 1536 blocks = exactly 6 blocks/CU
// (uniform, no straggler tail); unroll-4 j-loop batches LDS reads and keeps
// 12 independent IEEE-div chains in flight (VALUBusy ~83%).
// APT=6 regressed (round 9): compiler caps at 60 VGPRs and serializes the
// chains — occupancy drops with no ILP gain. NO min-waves launch bound
// (round 7: a register cap spills state, +30 MB scratch traffic).
// best init = 0/bidx = 0 is exact (iou >= 0; strict > keeps first-max);
// IoU expression is FMA-contraction-free with IEEE div => decisions
// bit-identical to the fp32 numpy reference.
template <bool USE_FLAGS>
__global__ __launch_bounds__(BLK) void k1_classify(
    const float* __restrict__ anchors,
    const float* __restrict__ gt,
    const float* __restrict__ deltas,
    float* __restrict__ out,
    int* __restrict__ cnt_blk,          // USE_FLAGS: [NB*GX]; else counts[NB]
    unsigned char* __restrict__ flags)
{
  __shared__ float4 gbox[NGT];
  __shared__ float  garea[NGT];
  __shared__ int    s_cnt;
  const int b   = blockIdx.y;
  const int tid = threadIdx.x;

  if (tid == 0) s_cnt = 0;
  if (tid < NGT) {
    float4 g = reinterpret_cast<const float4*>(gt)[b * NGT + tid];
    gbox[tid]  = g;
    garea[tid] = fmaxf(g.z - g.x, 0.0f) * fmaxf(g.w - g.y, 0.0f);
  }
  __syncthreads();

  const int base = blockIdx.x * (BLK * APT) + tid;

  float4 a[APT];
  float  areaA[APT], best[APT];
  int    bidx[APT];
#pragma unroll
  for (int t = 0; t < APT; ++t) {
    a[t] = reinterpret_cast<const float4*>(anchors)[base + t * BLK];
    areaA[t] = fmaxf(a[t].z - a[t].x, 0.0f) * fmaxf(a[t].w - a[t].y, 0.0f);
    best[t] = 0.0f;
    bidx[t] = 0;
  }

#pragma unroll 4
  for (int j = 0; j < NGT; ++j) {
    const float4 g  = gbox[j];
    const float  ga = garea[j];
#pragma unroll
    for (int t = 0; t < APT; ++t) {
      float yi = fmaxf(a[t].x, g.x);
      float xi = fmaxf(a[t].y, g.y);
      float ya = fminf(a[t].z, g.z);
      float xa = fminf(a[t].w, g.w);
      float inter = fmaxf(ya - yi, 0.0f) * fmaxf(xa - xi, 0.0f);
      float den   = ((areaA[t] + ga) - inter) + 1e-5f;   // union + EPS, exact order
      float iou   = (10000.0f * inter) / den;            // IEEE div
      bool upd = iou > best[t];                          // first-max == jnp.argmax
      best[t] = upd ? iou : best[t];
      bidx[t] = upd ? j   : bidx[t];
    }
  }

  int npos = 0;
#pragma unroll
  for (int t = 0; t < APT; ++t) {
    const int i = base + t * BLK;
    const bool pos = best[t] > 5000.0f;

    const float4 d = reinterpret_cast<const float4*>(deltas)[b * NAC + i];
    const float wb = a[t].w - a[t].y, hb = a[t].z - a[t].x;
    const float xc = a[t].y + 0.5f * wb + wb * d.x;
    const float yc = a[t].x + 0.5f * hb + hb * d.y;
    const float w_ = wb * __expf(d.z);
    const float h_ = hb * __expf(d.w);

    float* rowp = out + ((size_t)b * NAC + i) * 8;
    reinterpret_cast<float4*>(rowp)[0] =
        make_float4(yc - 0.5f * h_, xc - 0.5f * w_, yc + 0.5f * h_, xc + 0.5f * w_);
    if (USE_FLAGS) {
      reinterpret_cast<float4*>(rowp)[1] = make_float4(0.f, 0.f, 0.f, 0.f);
      flags[(size_t)b * NAC + i] = pos ? (unsigned char)(bidx[t] + 1) : 0u;
    } else {
      reinterpret_cast<float4*>(rowp)[1] =
          make_float4(pos ? (float)(bidx[t] + 1) : 0.0f, 0.f, 0.f, 0.f);
    }

    unsigned long long m = __ballot(pos);
    if ((tid & 63) == 0) npos += (int)__popcll(m);
  }
  if ((tid & 63) == 0 && npos)
    atomicAdd(&s_cnt, npos);
  __syncthreads();

  if (tid == 0) {
    if (USE_FLAGS) cnt_blk[b * GX + blockIdx.x] = s_cnt;  // written once, no memset
    else if (s_cnt) atomicAdd(&cnt_blk[b], s_cnt);
  }
}

// ---------------- Kernel 2a (flags): sum block counts, sparse sampling -------
__global__ __launch_bounds__(256) void k2_flags(
    const float* __restrict__ anchors,
    const float* __restrict__ gt,
    float* __restrict__ out,
    const int* __restrict__ cnt_blk,
    const unsigned char* __restrict__ flags,
    uint32_t kp0, uint32_t kp1)
{
  __shared__ int s_tot;
  const int b   = blockIdx.y;
  const int tid = threadIdx.x;

  if (tid == 0) s_tot = 0;
  __syncthreads();
  if (tid < GX) atomicAdd(&s_tot, cnt_blk[b * GX + tid]);
  __syncthreads();
  const float th = 128.0f / ((float)s_tot + 1e-6f);

  const int chunk = blockIdx.x * 256 + tid;   // 16 rows per thread
  uint4 fv = reinterpret_cast<const uint4*>(flags + (size_t)b * NAC)[chunk];
  if ((fv.x | fv.y | fv.z | fv.w) == 0u) return;

  const uint32_t words[4] = { fv.x, fv.y, fv.z, fv.w };
  const int base_i = chunk * 16;

#pragma unroll
  for (int w = 0; w < 4; ++w) {
    uint32_t wd = words[w];
    while (wd) {
      const int byte = __ffs(wd) / 8;        // flag <= 64 keeps byte MSB clear
      const int fl   = (wd >> (byte * 8)) & 0xFF;
      wd &= ~(0xFFu << (byte * 8));
      const int i = base_i + w * 4 + byte;
      const int f = b * NAC + i;

      uint32_t o0, o1;
      threefry2x32(kp0, kp1, 0u, (uint32_t)f, &o0, &o1);
      const uint32_t bits = o0 ^ o1;
      union { uint32_t u; float flt; } cv;
      cv.u = (bits >> 9) | 0x3F800000u;
      if (cv.flt - 1.0f < th) {
        const float4 a = reinterpret_cast<const float4*>(anchors)[i];
        const float4 g = reinterpret_cast<const float4*>(gt)[b * NGT + (fl - 1)];
        bbox2delta_store(a, g, out + (size_t)f * 8 + 4);
      }
    }
  }
}

// ---------------- Kernel 2b (fallback, proven): flag in out[4] ---------------
__global__ __launch_bounds__(256) void k2_fallback(
    const float* __restrict__ anchors,
    const float* __restrict__ gt,
    float* __restrict__ out,
    const int* __restrict__ counts,
    uint32_t kp0, uint32_t kp1)
{
  const int b = blockIdx.y;
  const int i = blockIdx.x * 256 + threadIdx.x;
  const int f = b * NAC + i;
  float* rowp = out + (size_t)f * 8;

  const float flag = rowp[4];
  if (flag == 0.0f) return;

  const float th = 128.0f / ((float)counts[b] + 1e-6f);

  uint32_t o0, o1;
  threefry2x32(kp0, kp1, 0u, (uint32_t)f, &o0, &o1);
  const uint32_t bits = o0 ^ o1;
  union { uint32_t u; float flt; } cv;
  cv.u = (bits >> 9) | 0x3F800000u;

  if (cv.flt - 1.0f < th) {
    const float4 a = reinterpret_cast<const float4*>(anchors)[i];
    const float4 g = reinterpret_cast<const float4*>(gt)[b * NGT + ((int)flag - 1)];
    bbox2delta_store(a, g, rowp + 4);
  } else {
    reinterpret_cast<float4*>(rowp)[1] = make_float4(0.f, 0.f, 0.f, 0.f);
  }
}

extern "C" void kernel_launch(void* const* d_in, const int* in_sizes, int n_in,
                              void* d_out, int out_size, void* d_ws, size_t ws_size,
                              hipStream_t stream)
{
  const float* anchors = (const float*)d_in[0];
  const float* gt      = (const float*)d_in[1];
  const float* deltas  = (const float*)d_in[2];
  float* out  = (float*)d_out;
  int* cnt_blk = (int*)d_ws;                                // [NB*GX] ints
  unsigned char* flags = (unsigned char*)d_ws + 8192;       // [NB*NAC] bytes

  const bool use_flags = ws_size >= (size_t)(8192 + NB * NAC);

  // kp = jax.random.split(jax.random.key(42))[0], threefry_partitionable:
  // kp = threefry2x32((0,42), 0, 0), full pair. (Verified rounds 2/3/5-9.)
  uint32_t kp0, kp1;
  threefry2x32(0u, 42u, 0u, 0u, &kp0, &kp1);

  dim3 g1(GX, NB);   // (192, 8) = 1536 blocks, 6/CU exact
  if (use_flags) {
    k1_classify<true><<<g1, dim3(BLK), 0, stream>>>(anchors, gt, deltas, out,
                                                    cnt_blk, flags);
    dim3 g2(NAC / 16 / 256, NB);   // (36, 8)
    k2_flags<<<g2, dim3(256), 0, stream>>>(anchors, gt, out, cnt_blk, flags,
                                           kp0, kp1);
  } else {
    hipMemsetAsync(cnt_blk, 0, NB * sizeof(int), stream);
    k1_classify<false><<<g1, dim3(BLK), 0, stream>>>(anchors, gt, deltas, out,
                                                     cnt_blk, nullptr);
    dim3 g2(NAC / 256, NB);        // (576, 8)
    k2_fallback<<<g2, dim3(256), 0, stream>>>(anchors, gt, out, cnt_blk,
                                              kp0, kp1);
  }
}